// Round 1
// 925.287 us; speedup vs baseline: 1.0265x; 1.0265x over previous
//
#include <hip/hip_runtime.h>
#include <cstddef>
#include <cstdint>

#define D_EMB   1408
#define NHEADS  16
#define HD      88
#define BATCH   16
#define SEQ     577
#define M_ROWS  (BATCH * SEQ)   // 9232
#define N_QKV   (3 * D_EMB)     // 4224
#define QKL_N   2816            // qkv-lo row stride (Q|K thirds only)
#define SP      640             // seq padded to 10 x 64 for Vt
#define ATT_SCALE 0.10660035817780521f

#define QT 64
#define KT 64

typedef __attribute__((ext_vector_type(8))) short bf16x8;
typedef __attribute__((ext_vector_type(4))) float f32x4;
typedef unsigned short u16;

static __device__ __forceinline__ u16 f2bf(float x) {
  union { float f; unsigned u; } v; v.f = x;
  unsigned r = v.u + 0x7fff + ((v.u >> 16) & 1);   // RNE
  return (u16)(r >> 16);
}
static __device__ __forceinline__ float bf2f(u16 h) {
  union { unsigned u; float f; } v; v.u = ((unsigned)h) << 16;
  return v.f;
}
static __device__ __forceinline__ void split_hl(float x, u16* hi, u16* lo) {
  u16 h = f2bf(x);
  *hi = h;
  *lo = f2bf(x - bf2f(h));
}

// async global->LDS, 16 B per lane; lds dest = wave-uniform base + lane*16
static __device__ __forceinline__ void async16(const u16* g, u16* l) {
  __builtin_amdgcn_global_load_lds(
      (const __attribute__((address_space(1))) unsigned int*)g,
      (__attribute__((address_space(3))) unsigned int*)l, 16, 0, 0);
}

// ---------------------------------------------------------------------------
// split: X fp32 -> H,L bf16
// ---------------------------------------------------------------------------
__global__ __launch_bounds__(256)
void split_kernel(const float* __restrict__ X, u16* __restrict__ H,
                  u16* __restrict__ L, int n4) {
  int i = blockIdx.x * 256 + threadIdx.x;
  if (i >= n4) return;
  float4 v = ((const float4*)X)[i];
  ushort4 h, l;
  split_hl(v.x, &h.x, &l.x);
  split_hl(v.y, &h.y, &l.y);
  split_hl(v.z, &h.z, &l.z);
  split_hl(v.w, &h.w, &l.w);
  ((ushort4*)H)[i] = h;
  ((ushort4*)L)[i] = l;
}

// ---------------------------------------------------------------------------
// transpose+split: W[K][N] fp32 -> Th,Tl[N][K] bf16
// ---------------------------------------------------------------------------
__global__ __launch_bounds__(256)
void transpose_split_kernel(const float* __restrict__ W, u16* __restrict__ Th,
                            u16* __restrict__ Tl, int K, int N) {
  __shared__ float tile[32][33];
  const int n0 = blockIdx.x * 32, k0 = blockIdx.y * 32;
  const int tx = threadIdx.x & 31, ty = threadIdx.x >> 5;
#pragma unroll
  for (int i = 0; i < 4; ++i) {
    int k = ty + i * 8;
    tile[k][tx] = W[(size_t)(k0 + k) * N + n0 + tx];
  }
  __syncthreads();
#pragma unroll
  for (int i = 0; i < 4; ++i) {
    int n = ty + i * 8;
    float v = tile[tx][n];
    u16 h, l;
    split_hl(v, &h, &l);
    Th[(size_t)(n0 + n) * K + k0 + tx] = h;
    Tl[(size_t)(n0 + n) * K + k0 + tx] = l;
  }
}

// ---------------------------------------------------------------------------
// V transpose: qkvH V-third -> vt[bh][d][s], [256][96][640], zero-padded.
// ---------------------------------------------------------------------------
__global__ __launch_bounds__(256)
void vtrans_kernel(const u16* __restrict__ qkvh, u16* __restrict__ vt) {
  __shared__ u16 tile[64][96];   // [s][d]
  const int st = blockIdx.x, bh = blockIdx.y;
  const int b = bh >> 4, h = bh & 15;
  const int tid = threadIdx.x;
  const int s0 = st * 64;
  for (int idx = tid; idx < 64 * 22; idx += 256) {
    int j = idx / 22, c4 = (idx % 22) * 4;
    int s = s0 + j;
    ushort4 v = make_ushort4(0, 0, 0, 0);
    if (s < SEQ)
      v = *(const ushort4*)(qkvh + (size_t)(b * SEQ + s) * N_QKV + 2 * D_EMB + h * HD + c4);
    *(ushort4*)&tile[j][c4] = v;
  }
  if (tid < 64) {
    bf16x8 z = {0, 0, 0, 0, 0, 0, 0, 0};
    *(bf16x8*)&tile[tid][88] = z;
  }
  __syncthreads();
  for (int idx = tid; idx < 96 * 8; idx += 256) {
    int d = idx >> 3, c8 = (idx & 7) * 8;
    bf16x8 o;
#pragma unroll
    for (int e = 0; e < 8; ++e) o[e] = (short)tile[c8 + e][d];
    *(bf16x8*)(vt + ((size_t)bh * 96 + d) * SP + s0 + c8) = o;
  }
}

// ---------------------------------------------------------------------------
// 3-product hi/lo bf16 MFMA GEMM, counted-vmcnt phase pipeline (T3+T4+T2+T5).
// BM=256 x BN=128 tile, 8 waves (4M x 2N), per-wave 64x64, K=1408 fixed.
// Stage unit = one K-half (32 cols) of {Ah,Al,Bh,Bl} = 48 KiB; 3-slot LDS
// ring (144 KiB). 44 phases; each phase: ds_read frags || issue next-slot
// global_load_lds -> vmcnt(6) -> s_barrier -> lgkmcnt(0) -> 48 MFMA -> barrier.
// vmcnt never drains to 0 in the main loop (2 slots always in flight).
// Swizzle: 16B block q of row r stored at phys q ^ ((r>>1)&3): with the
// (r&1) bank bit this spreads 16 lanes over 8 slots -> 2-way (free).
// XCD-swizzled 1-D grid as before (bands multiple of 8).
// MODE 0: fp32 out.  MODE 1: hi -> Ch[row*N+col]; lo -> Cl[row*2816+col].
// ---------------------------------------------------------------------------
#define KDIM   1408
#define BMT    256
#define BNT    128
#define SLOT_E 24576          // elems per slot: A 2*8192 + B 2*4096
#define AS_H   0
#define AS_L   8192
#define BS_H   16384
#define BS_L   20480

#define STAGE(SLOTP, SSN)                                                 \
  {                                                                       \
    const int k0s = (SSN) * 32;                                           \
    u16* Ls = &Lds[SLOTP][0];                                             \
    async16(Ah + srcA0 + k0s, Ls + AS_H + ldsA0);                         \
    async16(Ah + srcA1 + k0s, Ls + AS_H + ldsA1);                         \
    async16(Al + srcA0 + k0s, Ls + AS_L + ldsA0);                         \
    async16(Al + srcA1 + k0s, Ls + AS_L + ldsA1);                         \
    async16(Bh + srcB0 + k0s, Ls + BS_H + ldsB0);                         \
    async16(Bl + srcB0 + k0s, Ls + BS_L + ldsB0);                         \
  }

#define PHASE(SLOT, NXSLOT, SSN, DO_STAGE, VM)                            \
  {                                                                       \
    const u16* Lb = &Lds[SLOT][0];                                        \
    bf16x8 fah[4], fal[4], fbh[4], fbl[4];                                \
    _Pragma("unroll")                                                     \
    for (int i = 0; i < 4; ++i) {                                         \
      fah[i] = *(const bf16x8*)&Lb[AS_H + offA[i]];                       \
      fal[i] = *(const bf16x8*)&Lb[AS_L + offA[i]];                       \
      fbh[i] = *(const bf16x8*)&Lb[BS_H + offB[i]];                       \
      fbl[i] = *(const bf16x8*)&Lb[BS_L + offB[i]];                       \
    }                                                                     \
    if (DO_STAGE) STAGE(NXSLOT, SSN);                                     \
    asm volatile("s_waitcnt vmcnt(" #VM ")" ::: "memory");                \
    __builtin_amdgcn_s_barrier();                                         \
    asm volatile("s_waitcnt lgkmcnt(0)" ::: "memory");                    \
    __builtin_amdgcn_sched_barrier(0);                                    \
    __builtin_amdgcn_s_setprio(1);                                        \
    _Pragma("unroll")                                                     \
    for (int i = 0; i < 4; ++i) {                                         \
      _Pragma("unroll")                                                   \
      for (int j = 0; j < 4; ++j) {                                       \
        acc[i][j] = __builtin_amdgcn_mfma_f32_16x16x32_bf16(fah[i], fbh[j], acc[i][j], 0, 0, 0); \
        acc[i][j] = __builtin_amdgcn_mfma_f32_16x16x32_bf16(fah[i], fbl[j], acc[i][j], 0, 0, 0); \
        acc[i][j] = __builtin_amdgcn_mfma_f32_16x16x32_bf16(fal[i], fbh[j], acc[i][j], 0, 0, 0); \
      }                                                                   \
    }                                                                     \
    __builtin_amdgcn_s_setprio(0);                                        \
    __builtin_amdgcn_s_barrier();                                         \
  }

template <int MODE>
__global__ __launch_bounds__(512)
void gemm8p_kernel(const u16* __restrict__ Ah, const u16* __restrict__ Al,
                   const u16* __restrict__ Bh, const u16* __restrict__ Bl,
                   const float* __restrict__ bias,
                   float* __restrict__ Cf, u16* __restrict__ Ch, u16* __restrict__ Cl,
                   int M, int N, int NX) {
  const int lin  = blockIdx.x;
  const int xcd  = lin & 7;
  const int t    = lin >> 3;
  const int band = xcd + 8 * (t / NX);
  const int bm0  = band * BMT;
  if (bm0 >= M) return;
  const int bn0  = (t % NX) * BNT;

  __shared__ u16 Lds[3][SLOT_E];   // 144 KiB

  const int tid  = threadIdx.x;
  const int lane = tid & 63;
  const int w    = tid >> 6;           // 8 waves
  const int quad = lane >> 4, lc = lane & 15;
  const int wm   = w >> 1, wn = w & 1; // 4M x 2N

  // ---- staging source/dest (per thread, add ss*32 per slot) ----
  size_t srcA0, srcA1, srcB0;
  int ldsA0, ldsA1, ldsB0;
  {
    // A load 0: blocks tid -> rows 0..127 of the band
    int r0 = tid >> 2, q0 = tid & 3;
    int ra0 = bm0 + r0; if (ra0 > M - 1) ra0 = M - 1;
    srcA0 = (size_t)ra0 * KDIM + (size_t)((q0 ^ ((r0 >> 1) & 3)) * 8);
    ldsA0 = w * 512;
    // A load 1: blocks 512+tid -> rows 128..255
    int r1 = 128 + r0;
    int ra1 = bm0 + r1; if (ra1 > M - 1) ra1 = M - 1;
    srcA1 = (size_t)ra1 * KDIM + (size_t)((q0 ^ ((r1 >> 1) & 3)) * 8);
    ldsA1 = 4096 + w * 512;
    // B: blocks tid -> rows 0..127 of the n-block (N multiple of 128)
    srcB0 = (size_t)(bn0 + r0) * KDIM + (size_t)((q0 ^ ((r0 >> 1) & 3)) * 8);
    ldsB0 = w * 512;
  }

  // ---- fragment read offsets (elems within array region) ----
  // phys block = quad ^ ((row>>1)&3); row>>1 mod 4 == (lc>>1)&3 here.
  int offA[4], offB[4];
  {
    const int qphys = quad ^ ((lc >> 1) & 3);
#pragma unroll
    for (int i = 0; i < 4; ++i) {
      offA[i] = (wm * 64 + i * 16 + lc) * 32 + qphys * 8;
      offB[i] = (wn * 64 + i * 16 + lc) * 32 + qphys * 8;
    }
  }

  f32x4 acc[4][4];
#pragma unroll
  for (int i = 0; i < 4; ++i)
#pragma unroll
    for (int j = 0; j < 4; ++j) acc[i][j] = (f32x4){0.f, 0.f, 0.f, 0.f};

  // ---- prologue: stage slots 0,1; wait slot 0 ----
  STAGE(0, 0);
  STAGE(1, 1);
  asm volatile("s_waitcnt vmcnt(6)" ::: "memory");
  __builtin_amdgcn_s_barrier();

  // ---- main loop: 42 phases (content 0..41), 3 per iteration ----
#pragma unroll 1
  for (int u = 0; u < 14; ++u) {
    const int s = u * 3;
    PHASE(0, 2, s + 2, true, 6);
    PHASE(1, 0, s + 3, true, 6);
    PHASE(2, 1, s + 4, true, 6);
  }
  // ---- tail: content 42 (phys 0), 43 (phys 1); drain ----
  PHASE(0, 0, 0, false, 0);
  PHASE(1, 0, 0, false, 0);

  // ---- epilogue: C/D layout col=lc, row=quad*4+reg ----
#pragma unroll
  for (int j = 0; j < 4; ++j) {
    int col = bn0 + wn * 64 + j * 16 + lc;
    float bj = bias[col];
#pragma unroll
    for (int i = 0; i < 4; ++i) {
#pragma unroll
      for (int rg = 0; rg < 4; ++rg) {
        int row = bm0 + wm * 64 + i * 16 + quad * 4 + rg;
        if (row < M) {
          float v = acc[i][j][rg] + bj;
          if (MODE == 0) {
            Cf[(size_t)row * N + col] = v;
          } else {
            u16 hh, ll;
            split_hl(v, &hh, &ll);
            Ch[(size_t)row * N + col] = hh;
            if (col < QKL_N) Cl[(size_t)row * QKL_N + col] = ll;
          }
        }
      }
    }
  }
}

// ---------------------------------------------------------------------------
// MFMA flash attention v2 (round-4, kept). Block = (b,h,64-q tile).
// ---------------------------------------------------------------------------
__global__ __launch_bounds__(256)
void attn_kernel2(const u16* __restrict__ qkvh, const u16* __restrict__ qkvl,
                  const u16* __restrict__ vt,
                  u16* __restrict__ outh, u16* __restrict__ outl) {
  __shared__ u16 Khi[KT][104];   // stride 52 words == 20 mod 32 -> <=2-way
  __shared__ u16 Klo[KT][104];
  __shared__ u16 Vs[96][72];     // stride 36 words == 4 mod 32 -> <=2-way
  __shared__ u16 Pb[QT][72];

  const int tid  = threadIdx.x;
  const int lane = tid & 63;
  const int wv   = tid >> 6;
  const int quad = lane >> 4;
  const int lc   = lane & 15;

  const int qt = blockIdx.x, h = blockIdx.y, b = blockIdx.z;
  const int q0 = qt * QT;

  if (tid < KT) {
    bf16x8 z = {0, 0, 0, 0, 0, 0, 0, 0};
    *(bf16x8*)&Khi[tid][88] = z;
    *(bf16x8*)&Klo[tid][88] = z;
  }

  bf16x8 qh[3], ql[3];
  {
    const bf16x8 z = {0, 0, 0, 0, 0, 0, 0, 0};
    int qrow = q0 + wv * 16 + lc;
    bool qv = qrow < SEQ;
    size_t bh_ = (size_t)(b * SEQ + (qv ? qrow : 0));
#pragma unroll
    for (int ks = 0; ks < 3; ++ks) {
      if (!qv || (ks == 2 && quad == 3)) {
        qh[ks] = z; ql[ks] = z;
      } else {
        qh[ks] = *(const bf16x8*)(qkvh + bh_ * N_QKV + h * HD + ks * 32 + quad * 8);
        ql[ks] = *(const bf16x8*)(qkvl + bh_ * QKL_N + h * HD + ks * 32 + quad * 8);
      }
    }
  }

  float mrow[4], lrow[4];
#pragma unroll
  for (int r = 0; r < 4; ++r) { mrow[r] = -INFINITY; lrow[r] = 0.f; }
  f32x4 oacc[6];
#pragma unroll
  for (int nn = 0; nn < 6; ++nn) oacc[nn] = (f32x4){0.f, 0.f, 0.f, 0.f};

  const u16* vsrc = vt + (size_t)(b * 16 + h) * 96 * SP;

  for (int kt = 0; kt < SP / KT; ++kt) {
    const int k0 = kt * KT;
    __syncthreads();

    for (int idx = tid; idx < KT * 22; idx += 256) {
      int j = idx / 22, c4 = (idx % 22) * 4;
      int s = k0 + j;
      ushort4 kh = make_ushort4(0, 0, 0, 0), kl = make_ushort4(0, 0, 0, 0);
      if (s < SEQ) {
        size_t rb = (size_t)(b * SEQ + s);
        kh = *(const ushort4*)(qkvh + rb * N_QKV + D_EMB + h * HD + c4);
        kl = *(const ushort4*)(qkvl + rb * QKL_N + D_EMB + h * HD + c4);
      }
      *(ushort4*)&Khi[j][c4] = kh;
      *(ushort4*)&Klo[j][c4] = kl;
    }
    for (int idx = tid; idx < 96 * 8; idx += 256) {
      int d = idx >> 3, c8 = (idx & 7) * 8;
      *(bf16x8*)&Vs[d][c8] = *(const bf16x8*)(vsrc + (size_t)d * SP + k0 + c8);
    }
    __syncthreads();

    f32x4 sc[4];
#pragma unroll
    for (int t = 0; t < 4; ++t) {
      f32x4 a = (f32x4){0.f, 0.f, 0.f, 0.f};
#pragma unroll
      for (int ks = 0; ks < 3; ++ks) {
        bf16x8 kh = *(const bf16x8*)&Khi[t * 16 + lc][ks * 32 + quad * 8];
        bf16x8 kl = *(const bf16x8*)&Klo[t * 16 + lc][ks * 32 + quad * 8];
        a = __builtin_amdgcn_mfma_f32_16x16x32_bf16(qh[ks], kh, a, 0, 0, 0);
        a = __builtin_amdgcn_mfma_f32_16x16x32_bf16(qh[ks], kl, a, 0, 0, 0);
        a = __builtin_amdgcn_mfma_f32_16x16x32_bf16(ql[ks], kh, a, 0, 0, 0);
      }
      sc[t] = a;
    }
#pragma unroll
    for (int t = 0; t < 4; ++t) {
      bool valid = (k0 + t * 16 + lc) < SEQ;
#pragma unroll
      for (int r = 0; r < 4; ++r)
        sc[t][r] = valid ? sc[t][r] * ATT_SCALE : -INFINITY;
    }

    float alpha[4];
#pragma unroll
    for (int r = 0; r < 4; ++r) {
      float v = fmaxf(fmaxf(sc[0][r], sc[1][r]), fmaxf(sc[2][r], sc[3][r]));
      v = fmaxf(v, __shfl_xor(v, 1));
      v = fmaxf(v, __shfl_xor(v, 2));
      v = fmaxf(v, __shfl_xor(v, 4));
      v = fmaxf(v, __shfl_xor(v, 8));
      float mnew = fmaxf(mrow[r], v);
      alpha[r] = expf(mrow[r] - mnew);
      mrow[r] = mnew;
      float s = 0.f;
#pragma unroll
      for (int t = 0; t < 4; ++t) {
        float p = expf(sc[t][r] - mnew);
        sc[t][r] = p;
        s += p;
      }
      s += __shfl_xor(s, 1);
      s += __shfl_xor(s, 2);
      s += __shfl_xor(s, 4);
      s += __shfl_xor(s, 8);
      lrow[r] = lrow[r] * alpha[r] + s;
    }
#pragma unroll
    for (int t = 0; t < 4; ++t)
#pragma unroll
      for (int r = 0; r < 4; ++r)
        Pb[wv * 16 + quad * 4 + r][t * 16 + lc] = f2bf(sc[t][r]);
#pragma unroll
    for (int nn = 0; nn < 6; ++nn)
#pragma unroll
      for (int r = 0; r < 4; ++r) oacc[nn][r] *= alpha[r];
    __syncthreads();

    bf16x8 p0 = *(const bf16x8*)&Pb[wv * 16 + lc][quad * 8];
    bf16x8 p1 = *(const bf16x8*)&Pb[wv * 16 + lc][32 + quad * 8];
#pragma unroll
    for (int nn = 0; nn < 6; ++nn) {
      bf16x8 v0 = *(const bf16x8*)&Vs[nn * 16 + lc][quad * 8];
      bf16x8 v1 = *(const bf16x8*)&Vs[nn * 16 + lc][32 + quad * 8];
      oacc[nn] = __builtin_amdgcn_mfma_f32_16x16x32_bf16(p0, v0, oacc[nn], 0, 0, 0);
      oacc[nn] = __builtin_amdgcn_mfma_f32_16x16x32_bf16(p1, v1, oacc[nn], 0, 0, 0);
    }
  }

#pragma unroll
  for (int r = 0; r < 4; ++r) {
    int s = q0 + wv * 16 + quad * 4 + r;
    if (s < SEQ) {
      float inv = 1.f / lrow[r];
      size_t base = (size_t)(b * SEQ + s) * D_EMB + h * HD;
#pragma unroll
      for (int nn = 0; nn < 6; ++nn) {
        int d = nn * 16 + lc;
        if (d < HD) {
          float v = oacc[nn][r] * inv;
          u16 hh, ll;
          split_hl(v, &hh, &ll);
          outh[base + d] = hh;
          outl[base + d] = ll;
        }
      }
    }
  }
}

// ---------------------------------------------------------------------------
extern "C" void kernel_launch(void* const* d_in, const int* in_sizes, int n_in,
                              void* d_out, int out_size, void* d_ws, size_t ws_size,
                              hipStream_t stream) {
  const float* hs    = (const float*)d_in[0];
  const float* wqkv  = (const float*)d_in[1];
  const float* bqkv  = (const float*)d_in[2];
  const float* wproj = (const float*)d_in[3];
  const float* bproj = (const float*)d_in[4];
  float* out = (float*)d_out;

  u16* qkvH = (u16*)d_ws;
  u16* qkvL = qkvH + (size_t)M_ROWS * N_QKV;
  u16* hsH  = qkvL + (size_t)M_ROWS * QKL_N;
  u16* hsL  = hsH + (size_t)M_ROWS * D_EMB;
  u16* vt   = hsL + (size_t)M_ROWS * D_EMB;
  u16* wtH  = vt;                                   // alias (disjoint lifetime)
  u16* wtL  = wtH + (size_t)N_QKV * D_EMB;
  u16* attnH = hsH;                                 // alias (hs dead after GEMM1)
  u16* attnL = hsL;

  // 1) split hidden_states
  {
    int n4 = (M_ROWS * D_EMB) / 4;
    split_kernel<<<(n4 + 255) / 256, 256, 0, stream>>>(hs, hsH, hsL, n4);
  }
  // 2) transpose+split w_qkv -> wt (in vt region)
  {
    dim3 g(N_QKV / 32, D_EMB / 32);
    transpose_split_kernel<<<g, 256, 0, stream>>>(wqkv, wtH, wtL, D_EMB, N_QKV);
  }
  // 3) QKV GEMM (counted-vmcnt pipeline + XCD swizzle): 33 cols x 40 bands
  {
    gemm8p_kernel<1><<<33 * 40, 512, 0, stream>>>(hsH, hsL, wtH, wtL, bqkv,
                                                  nullptr, qkvH, qkvL,
                                                  M_ROWS, N_QKV, 33);
  }
  // 4) V transpose (wt dead; vt region reused)
  {
    dim3 g(SP / 64, BATCH * NHEADS);
    vtrans_kernel<<<g, 256, 0, stream>>>(qkvH, vt);
  }
  // 5) attention
  {
    dim3 g(SP / QT, NHEADS, BATCH);
    attn_kernel2<<<g, 256, 0, stream>>>(qkvH, qkvL, vt, attnH, attnL);
  }
  // 6) transpose+split w_proj -> wt (vt dead)
  {
    dim3 g(D_EMB / 32, D_EMB / 32);
    transpose_split_kernel<<<g, 256, 0, stream>>>(wproj, wtH, wtL, D_EMB, D_EMB);
  }
  // 7) output projection: 11 cols x 40 bands
  {
    gemm8p_kernel<0><<<11 * 40, 512, 0, stream>>>(attnH, attnL, wtH, wtL, bproj,
                                                  out, nullptr, nullptr,
                                                  M_ROWS, D_EMB, 11);
  }
}

// Round 3
// 888.624 us; speedup vs baseline: 1.0689x; 1.0413x over previous
//
#include <hip/hip_runtime.h>
#include <cstddef>
#include <cstdint>

#define D_EMB   1408
#define NHEADS  16
#define HD      88
#define BATCH   16
#define SEQ     577
#define M_ROWS  (BATCH * SEQ)   // 9232
#define N_QKV   (3 * D_EMB)     // 4224
#define QKL_N   2816            // qkv-lo row stride (Q|K thirds only)
#define SP      640             // seq padded to 10 x 64 for Vt
#define ATT_SCALE 0.10660035817780521f

#define QT 64
#define KT 64

typedef __attribute__((ext_vector_type(8))) short bf16x8;
typedef __attribute__((ext_vector_type(4))) float f32x4;
typedef unsigned short u16;

static __device__ __forceinline__ u16 f2bf(float x) {
  union { float f; unsigned u; } v; v.f = x;
  unsigned r = v.u + 0x7fff + ((v.u >> 16) & 1);   // RNE
  return (u16)(r >> 16);
}
static __device__ __forceinline__ float bf2f(u16 h) {
  union { unsigned u; float f; } v; v.u = ((unsigned)h) << 16;
  return v.f;
}
static __device__ __forceinline__ void split_hl(float x, u16* hi, u16* lo) {
  u16 h = f2bf(x);
  *hi = h;
  *lo = f2bf(x - bf2f(h));
}

// async global->LDS, 16 B per lane; lds dest = wave-uniform base + lane*16
static __device__ __forceinline__ void async16(const u16* g, u16* l) {
  __builtin_amdgcn_global_load_lds(
      (const __attribute__((address_space(1))) unsigned int*)g,
      (__attribute__((address_space(3))) unsigned int*)l, 16, 0, 0);
}

// ---------------------------------------------------------------------------
// split: X fp32 -> H,L bf16
// ---------------------------------------------------------------------------
__global__ __launch_bounds__(256)
void split_kernel(const float* __restrict__ X, u16* __restrict__ H,
                  u16* __restrict__ L, int n4) {
  int i = blockIdx.x * 256 + threadIdx.x;
  if (i >= n4) return;
  float4 v = ((const float4*)X)[i];
  ushort4 h, l;
  split_hl(v.x, &h.x, &l.x);
  split_hl(v.y, &h.y, &l.y);
  split_hl(v.z, &h.z, &l.z);
  split_hl(v.w, &h.w, &l.w);
  ((ushort4*)H)[i] = h;
  ((ushort4*)L)[i] = l;
}

// ---------------------------------------------------------------------------
// transpose+split: W[K][N] fp32 -> Th,Tl[N][K] bf16
// ---------------------------------------------------------------------------
__global__ __launch_bounds__(256)
void transpose_split_kernel(const float* __restrict__ W, u16* __restrict__ Th,
                            u16* __restrict__ Tl, int K, int N) {
  __shared__ float tile[32][33];
  const int n0 = blockIdx.x * 32, k0 = blockIdx.y * 32;
  const int tx = threadIdx.x & 31, ty = threadIdx.x >> 5;
#pragma unroll
  for (int i = 0; i < 4; ++i) {
    int k = ty + i * 8;
    tile[k][tx] = W[(size_t)(k0 + k) * N + n0 + tx];
  }
  __syncthreads();
#pragma unroll
  for (int i = 0; i < 4; ++i) {
    int n = ty + i * 8;
    float v = tile[tx][n];
    u16 h, l;
    split_hl(v, &h, &l);
    Th[(size_t)(n0 + n) * K + k0 + tx] = h;
    Tl[(size_t)(n0 + n) * K + k0 + tx] = l;
  }
}

// ---------------------------------------------------------------------------
// V transpose: qkvH V-third -> vt[bh][d][s], [256][96][640], zero-padded.
// ---------------------------------------------------------------------------
__global__ __launch_bounds__(256)
void vtrans_kernel(const u16* __restrict__ qkvh, u16* __restrict__ vt) {
  __shared__ u16 tile[64][96];   // [s][d]
  const int st = blockIdx.x, bh = blockIdx.y;
  const int b = bh >> 4, h = bh & 15;
  const int tid = threadIdx.x;
  const int s0 = st * 64;
  for (int idx = tid; idx < 64 * 22; idx += 256) {
    int j = idx / 22, c4 = (idx % 22) * 4;
    int s = s0 + j;
    ushort4 v = make_ushort4(0, 0, 0, 0);
    if (s < SEQ)
      v = *(const ushort4*)(qkvh + (size_t)(b * SEQ + s) * N_QKV + 2 * D_EMB + h * HD + c4);
    *(ushort4*)&tile[j][c4] = v;
  }
  if (tid < 64) {
    bf16x8 z = {0, 0, 0, 0, 0, 0, 0, 0};
    *(bf16x8*)&tile[tid][88] = z;
  }
  __syncthreads();
  for (int idx = tid; idx < 96 * 8; idx += 256) {
    int d = idx >> 3, c8 = (idx & 7) * 8;
    bf16x8 o;
#pragma unroll
    for (int e = 0; e < 8; ++e) o[e] = (short)tile[c8 + e][d];
    *(bf16x8*)(vt + ((size_t)bh * 96 + d) * SP + s0 + c8) = o;
  }
}

// ---------------------------------------------------------------------------
// 3-product hi/lo bf16 MFMA GEMM, deep counted-vmcnt pipeline.
// BM=256 x BN=128 tile, 8 waves (4M x 2N), per-wave 64x64, K=1408 fixed.
// Stage unit = one K-32 slot of {Ah,Al,Bh,Bl} = 48 KiB; 3-slot LDS ring
// (144 KiB), stage-ahead-2. Each slot = 3 sub-phases (quadrant-split MFMA):
//   ph0: 8 ds_read (fa01,fb01) | 2 stage -> BAR -> lgkm0 -> 12 MFMA -> BAR
//   ph1: 4 ds_read (fb23)      | 2 stage -> BAR -> lgkm0 -> 12 MFMA -> BAR
//   ph2: 4 ds_read (fa23)      | 2 stage -> BAR -> lgkm0 -> 24 MFMA -> vmcnt(6) -> BAR
// vmcnt(6) once per slot: waits slot s+1 (issued across slot s-1, ~4-6
// sub-phases earlier => ~1000+ cyc prefetch distance, covers HBM latency).
// Swizzle: 16B block q of row r at phys q ^ ((r>>1)&3) (conflict-free, R1-verified).
// XCD-swizzled 1-D grid (NX col-blocks of one M-band share an XCD's L2).
// MODE 0: fp32 out.  MODE 1: hi -> Ch[row*N+col]; lo -> Cl[row*2816+col].
// ---------------------------------------------------------------------------
#define KDIM   1408
#define BMT    256
#define BNT    128
#define SLOT_E 24576          // elems per slot: A 2*8192 + B 2*4096
#define AS_H   0
#define AS_L   8192
#define BS_H   16384
#define BS_L   20480

#define STAGE_A0(SLOTP, SSN)                                              \
  {                                                                       \
    const int k0s = (SSN) * 32;                                           \
    u16* Ls = &Lds[SLOTP][0];                                             \
    async16(Ah + srcA0 + k0s, Ls + AS_H + ldsA0);                         \
    async16(Al + srcA0 + k0s, Ls + AS_L + ldsA0);                         \
  }
#define STAGE_A1(SLOTP, SSN)                                              \
  {                                                                       \
    const int k0s = (SSN) * 32;                                           \
    u16* Ls = &Lds[SLOTP][0];                                             \
    async16(Ah + srcA1 + k0s, Ls + AS_H + ldsA1);                         \
    async16(Al + srcA1 + k0s, Ls + AS_L + ldsA1);                         \
  }
#define STAGE_B(SLOTP, SSN)                                               \
  {                                                                       \
    const int k0s = (SSN) * 32;                                           \
    u16* Ls = &Lds[SLOTP][0];                                             \
    async16(Bh + srcB0 + k0s, Ls + BS_H + ldsB0);                         \
    async16(Bl + srcB0 + k0s, Ls + BS_L + ldsB0);                         \
  }

#define MFMA3(I, J)                                                                               \
  acc[I][J] = __builtin_amdgcn_mfma_f32_16x16x32_bf16(fah[I], fbh[J], acc[I][J], 0, 0, 0);        \
  acc[I][J] = __builtin_amdgcn_mfma_f32_16x16x32_bf16(fah[I], fbl[J], acc[I][J], 0, 0, 0);        \
  acc[I][J] = __builtin_amdgcn_mfma_f32_16x16x32_bf16(fal[I], fbh[J], acc[I][J], 0, 0, 0);

#define PH_SYNC                                                           \
  __builtin_amdgcn_s_barrier();                                           \
  asm volatile("s_waitcnt lgkmcnt(0)" ::: "memory");                      \
  __builtin_amdgcn_sched_barrier(0);

// One K-32 slot: compute from phys PHYS, stage slot SSN into phys NXPHYS.
#define SLOT_RUN(PHYS, NXPHYS, SSN, DO_STAGE, VM)                         \
  {                                                                       \
    const u16* Lb = &Lds[PHYS][0];                                        \
    bf16x8 fah[4], fal[4], fbh[4], fbl[4];                                \
    /* ---- ph0: quadrant {0,1}x{0,1} ---- */                             \
    fah[0] = *(const bf16x8*)&Lb[AS_H + offA[0]];                         \
    fah[1] = *(const bf16x8*)&Lb[AS_H + offA[1]];                         \
    fal[0] = *(const bf16x8*)&Lb[AS_L + offA[0]];                         \
    fal[1] = *(const bf16x8*)&Lb[AS_L + offA[1]];                         \
    fbh[0] = *(const bf16x8*)&Lb[BS_H + offB[0]];                         \
    fbh[1] = *(const bf16x8*)&Lb[BS_H + offB[1]];                         \
    fbl[0] = *(const bf16x8*)&Lb[BS_L + offB[0]];                         \
    fbl[1] = *(const bf16x8*)&Lb[BS_L + offB[1]];                         \
    if (DO_STAGE) STAGE_A0(NXPHYS, SSN);                                  \
    PH_SYNC                                                               \
    __builtin_amdgcn_s_setprio(1);                                        \
    MFMA3(0, 0) MFMA3(0, 1) MFMA3(1, 0) MFMA3(1, 1)                       \
    __builtin_amdgcn_s_setprio(0);                                        \
    __builtin_amdgcn_s_barrier();                                         \
    /* ---- ph1: quadrant {0,1}x{2,3} ---- */                             \
    fbh[2] = *(const bf16x8*)&Lb[BS_H + offB[2]];                         \
    fbh[3] = *(const bf16x8*)&Lb[BS_H + offB[3]];                         \
    fbl[2] = *(const bf16x8*)&Lb[BS_L + offB[2]];                         \
    fbl[3] = *(const bf16x8*)&Lb[BS_L + offB[3]];                         \
    if (DO_STAGE) STAGE_A1(NXPHYS, SSN);                                  \
    PH_SYNC                                                               \
    __builtin_amdgcn_s_setprio(1);                                        \
    MFMA3(0, 2) MFMA3(0, 3) MFMA3(1, 2) MFMA3(1, 3)                       \
    __builtin_amdgcn_s_setprio(0);                                        \
    __builtin_amdgcn_s_barrier();                                         \
    /* ---- ph2: quadrants {2,3}x{0..3} ---- */                           \
    fah[2] = *(const bf16x8*)&Lb[AS_H + offA[2]];                         \
    fah[3] = *(const bf16x8*)&Lb[AS_H + offA[3]];                         \
    fal[2] = *(const bf16x8*)&Lb[AS_L + offA[2]];                         \
    fal[3] = *(const bf16x8*)&Lb[AS_L + offA[3]];                         \
    if (DO_STAGE) STAGE_B(NXPHYS, SSN);                                   \
    PH_SYNC                                                               \
    __builtin_amdgcn_s_setprio(1);                                        \
    MFMA3(2, 2) MFMA3(2, 3) MFMA3(3, 2) MFMA3(3, 3)                       \
    MFMA3(2, 0) MFMA3(2, 1) MFMA3(3, 0) MFMA3(3, 1)                       \
    __builtin_amdgcn_s_setprio(0);                                        \
    asm volatile("s_waitcnt vmcnt(" #VM ")" ::: "memory");                \
    __builtin_amdgcn_s_barrier();                                         \
  }

template <int MODE>
__global__ __launch_bounds__(512)
void gemm8p_kernel(const u16* __restrict__ Ah, const u16* __restrict__ Al,
                   const u16* __restrict__ Bh, const u16* __restrict__ Bl,
                   const float* __restrict__ bias,
                   float* __restrict__ Cf, u16* __restrict__ Ch, u16* __restrict__ Cl,
                   int M, int N, int NX) {
  const int lin  = blockIdx.x;
  const int xcd  = lin & 7;
  const int t    = lin >> 3;
  const int band = xcd + 8 * (t / NX);
  const int bm0  = band * BMT;
  if (bm0 >= M) return;
  const int bn0  = (t % NX) * BNT;

  __shared__ u16 Lds[3][SLOT_E];   // 144 KiB

  const int tid  = threadIdx.x;
  const int lane = tid & 63;
  const int w    = tid >> 6;           // 8 waves
  const int quad = lane >> 4, lc = lane & 15;
  const int wm   = w >> 1, wn = w & 1; // 4M x 2N

  // ---- staging source/dest (per thread, add ss*32 per slot) ----
  size_t srcA0, srcA1, srcB0;
  int ldsA0, ldsA1, ldsB0;
  {
    // A load 0: blocks tid -> rows 0..127 of the band
    int r0 = tid >> 2, q0 = tid & 3;
    int ra0 = bm0 + r0; if (ra0 > M - 1) ra0 = M - 1;
    srcA0 = (size_t)ra0 * KDIM + (size_t)((q0 ^ ((r0 >> 1) & 3)) * 8);
    ldsA0 = w * 512;
    // A load 1: blocks 512+tid -> rows 128..255
    int r1 = 128 + r0;
    int ra1 = bm0 + r1; if (ra1 > M - 1) ra1 = M - 1;
    srcA1 = (size_t)ra1 * KDIM + (size_t)((q0 ^ ((r1 >> 1) & 3)) * 8);
    ldsA1 = 4096 + w * 512;
    // B: blocks tid -> rows 0..127 of the n-block (N multiple of 128)
    srcB0 = (size_t)(bn0 + r0) * KDIM + (size_t)((q0 ^ ((r0 >> 1) & 3)) * 8);
    ldsB0 = w * 512;
  }

  // ---- fragment read offsets (elems within array region) ----
  // phys block = quad ^ ((row>>1)&3); row>>1 mod 4 == (lc>>1)&3 here.
  int offA[4], offB[4];
  {
    const int qphys = quad ^ ((lc >> 1) & 3);
#pragma unroll
    for (int i = 0; i < 4; ++i) {
      offA[i] = (wm * 64 + i * 16 + lc) * 32 + qphys * 8;
      offB[i] = (wn * 64 + i * 16 + lc) * 32 + qphys * 8;
    }
  }

  f32x4 acc[4][4];
#pragma unroll
  for (int i = 0; i < 4; ++i)
#pragma unroll
    for (int j = 0; j < 4; ++j) acc[i][j] = (f32x4){0.f, 0.f, 0.f, 0.f};

  // ---- prologue: stage slots 0,1; wait slot 0 (slot 1 stays in flight) ----
  STAGE_A0(0, 0); STAGE_A1(0, 0); STAGE_B(0, 0);
  STAGE_A0(1, 1); STAGE_A1(1, 1); STAGE_B(1, 1);
  asm volatile("s_waitcnt vmcnt(6)" ::: "memory");
  __builtin_amdgcn_s_barrier();

  // ---- main loop: slots 0..41, staging slots 2..43 (stage-ahead-2) ----
#pragma unroll 1
  for (int u = 0; u < 14; ++u) {
    const int s = u * 3;
    SLOT_RUN(0, 2, s + 2, true, 6);
    SLOT_RUN(1, 0, s + 3, true, 6);
    SLOT_RUN(2, 1, s + 4, true, 6);
  }
  // ---- tail: slots 42 (phys 0, drain slot 43), 43 (phys 1) ----
  SLOT_RUN(0, 0, 0, false, 0);
  SLOT_RUN(1, 0, 0, false, 0);

  // ---- epilogue: C/D layout col=lc, row=quad*4+reg ----
#pragma unroll
  for (int j = 0; j < 4; ++j) {
    int col = bn0 + wn * 64 + j * 16 + lc;
    float bj = bias[col];
#pragma unroll
    for (int i = 0; i < 4; ++i) {
#pragma unroll
      for (int rg = 0; rg < 4; ++rg) {
        int row = bm0 + wm * 64 + i * 16 + quad * 4 + rg;
        if (row < M) {
          float v = acc[i][j][rg] + bj;
          if (MODE == 0) {
            Cf[(size_t)row * N + col] = v;
          } else {
            u16 hh, ll;
            split_hl(v, &hh, &ll);
            Ch[(size_t)row * N + col] = hh;
            if (col < QKL_N) Cl[(size_t)row * QKL_N + col] = ll;
          }
        }
      }
    }
  }
}

// ---------------------------------------------------------------------------
// MFMA flash attention v2 (round-4, kept). Block = (b,h,64-q tile).
// ---------------------------------------------------------------------------
__global__ __launch_bounds__(256)
void attn_kernel2(const u16* __restrict__ qkvh, const u16* __restrict__ qkvl,
                  const u16* __restrict__ vt,
                  u16* __restrict__ outh, u16* __restrict__ outl) {
  __shared__ u16 Khi[KT][104];   // stride 52 words == 20 mod 32 -> <=2-way
  __shared__ u16 Klo[KT][104];
  __shared__ u16 Vs[96][72];     // stride 36 words == 4 mod 32 -> <=2-way
  __shared__ u16 Pb[QT][72];

  const int tid  = threadIdx.x;
  const int lane = tid & 63;
  const int wv   = tid >> 6;
  const int quad = lane >> 4;
  const int lc   = lane & 15;

  const int qt = blockIdx.x, h = blockIdx.y, b = blockIdx.z;
  const int q0 = qt * QT;

  if (tid < KT) {
    bf16x8 z = {0, 0, 0, 0, 0, 0, 0, 0};
    *(bf16x8*)&Khi[tid][88] = z;
    *(bf16x8*)&Klo[tid][88] = z;
  }

  bf16x8 qh[3], ql[3];
  {
    const bf16x8 z = {0, 0, 0, 0, 0, 0, 0, 0};
    int qrow = q0 + wv * 16 + lc;
    bool qv = qrow < SEQ;
    size_t bh_ = (size_t)(b * SEQ + (qv ? qrow : 0));
#pragma unroll
    for (int ks = 0; ks < 3; ++ks) {
      if (!qv || (ks == 2 && quad == 3)) {
        qh[ks] = z; ql[ks] = z;
      } else {
        qh[ks] = *(const bf16x8*)(qkvh + bh_ * N_QKV + h * HD + ks * 32 + quad * 8);
        ql[ks] = *(const bf16x8*)(qkvl + bh_ * QKL_N + h * HD + ks * 32 + quad * 8);
      }
    }
  }

  float mrow[4], lrow[4];
#pragma unroll
  for (int r = 0; r < 4; ++r) { mrow[r] = -INFINITY; lrow[r] = 0.f; }
  f32x4 oacc[6];
#pragma unroll
  for (int nn = 0; nn < 6; ++nn) oacc[nn] = (f32x4){0.f, 0.f, 0.f, 0.f};

  const u16* vsrc = vt + (size_t)(b * 16 + h) * 96 * SP;

  for (int kt = 0; kt < SP / KT; ++kt) {
    const int k0 = kt * KT;
    __syncthreads();

    for (int idx = tid; idx < KT * 22; idx += 256) {
      int j = idx / 22, c4 = (idx % 22) * 4;
      int s = k0 + j;
      ushort4 kh = make_ushort4(0, 0, 0, 0), kl = make_ushort4(0, 0, 0, 0);
      if (s < SEQ) {
        size_t rb = (size_t)(b * SEQ + s);
        kh = *(const ushort4*)(qkvh + rb * N_QKV + D_EMB + h * HD + c4);
        kl = *(const ushort4*)(qkvl + rb * QKL_N + D_EMB + h * HD + c4);
      }
      *(ushort4*)&Khi[j][c4] = kh;
      *(ushort4*)&Klo[j][c4] = kl;
    }
    for (int idx = tid; idx < 96 * 8; idx += 256) {
      int d = idx >> 3, c8 = (idx & 7) * 8;
      *(bf16x8*)&Vs[d][c8] = *(const bf16x8*)(vsrc + (size_t)d * SP + k0 + c8);
    }
    __syncthreads();

    f32x4 sc[4];
#pragma unroll
    for (int t = 0; t < 4; ++t) {
      f32x4 a = (f32x4){0.f, 0.f, 0.f, 0.f};
#pragma unroll
      for (int ks = 0; ks < 3; ++ks) {
        bf16x8 kh = *(const bf16x8*)&Khi[t * 16 + lc][ks * 32 + quad * 8];
        bf16x8 kl = *(const bf16x8*)&Klo[t * 16 + lc][ks * 32 + quad * 8];
        a = __builtin_amdgcn_mfma_f32_16x16x32_bf16(qh[ks], kh, a, 0, 0, 0);
        a = __builtin_amdgcn_mfma_f32_16x16x32_bf16(qh[ks], kl, a, 0, 0, 0);
        a = __builtin_amdgcn_mfma_f32_16x16x32_bf16(ql[ks], kh, a, 0, 0, 0);
      }
      sc[t] = a;
    }
#pragma unroll
    for (int t = 0; t < 4; ++t) {
      bool valid = (k0 + t * 16 + lc) < SEQ;
#pragma unroll
      for (int r = 0; r < 4; ++r)
        sc[t][r] = valid ? sc[t][r] * ATT_SCALE : -INFINITY;
    }

    float alpha[4];
#pragma unroll
    for (int r = 0; r < 4; ++r) {
      float v = fmaxf(fmaxf(sc[0][r], sc[1][r]), fmaxf(sc[2][r], sc[3][r]));
      v = fmaxf(v, __shfl_xor(v, 1));
      v = fmaxf(v, __shfl_xor(v, 2));
      v = fmaxf(v, __shfl_xor(v, 4));
      v = fmaxf(v, __shfl_xor(v, 8));
      float mnew = fmaxf(mrow[r], v);
      alpha[r] = expf(mrow[r] - mnew);
      mrow[r] = mnew;
      float s = 0.f;
#pragma unroll
      for (int t = 0; t < 4; ++t) {
        float p = expf(sc[t][r] - mnew);
        sc[t][r] = p;
        s += p;
      }
      s += __shfl_xor(s, 1);
      s += __shfl_xor(s, 2);
      s += __shfl_xor(s, 4);
      s += __shfl_xor(s, 8);
      lrow[r] = lrow[r] * alpha[r] + s;
    }
#pragma unroll
    for (int t = 0; t < 4; ++t)
#pragma unroll
      for (int r = 0; r < 4; ++r)
        Pb[wv * 16 + quad * 4 + r][t * 16 + lc] = f2bf(sc[t][r]);
#pragma unroll
    for (int nn = 0; nn < 6; ++nn)
#pragma unroll
      for (int r = 0; r < 4; ++r) oacc[nn][r] *= alpha[r];
    __syncthreads();

    bf16x8 p0 = *(const bf16x8*)&Pb[wv * 16 + lc][quad * 8];
    bf16x8 p1 = *(const bf16x8*)&Pb[wv * 16 + lc][32 + quad * 8];
#pragma unroll
    for (int nn = 0; nn < 6; ++nn) {
      bf16x8 v0 = *(const bf16x8*)&Vs[nn * 16 + lc][quad * 8];
      bf16x8 v1 = *(const bf16x8*)&Vs[nn * 16 + lc][32 + quad * 8];
      oacc[nn] = __builtin_amdgcn_mfma_f32_16x16x32_bf16(p0, v0, oacc[nn], 0, 0, 0);
      oacc[nn] = __builtin_amdgcn_mfma_f32_16x16x32_bf16(p1, v1, oacc[nn], 0, 0, 0);
    }
  }

#pragma unroll
  for (int r = 0; r < 4; ++r) {
    int s = q0 + wv * 16 + quad * 4 + r;
    if (s < SEQ) {
      float inv = 1.f / lrow[r];
      size_t base = (size_t)(b * SEQ + s) * D_EMB + h * HD;
#pragma unroll
      for (int nn = 0; nn < 6; ++nn) {
        int d = nn * 16 + lc;
        if (d < HD) {
          float v = oacc[nn][r] * inv;
          u16 hh, ll;
          split_hl(v, &hh, &ll);
          outh[base + d] = hh;
          outl[base + d] = ll;
        }
      }
    }
  }
}

// ---------------------------------------------------------------------------
extern "C" void kernel_launch(void* const* d_in, const int* in_sizes, int n_in,
                              void* d_out, int out_size, void* d_ws, size_t ws_size,
                              hipStream_t stream) {
  const float* hs    = (const float*)d_in[0];
  const float* wqkv  = (const float*)d_in[1];
  const float* bqkv  = (const float*)d_in[2];
  const float* wproj = (const float*)d_in[3];
  const float* bproj = (const float*)d_in[4];
  float* out = (float*)d_out;

  u16* qkvH = (u16*)d_ws;
  u16* qkvL = qkvH + (size_t)M_ROWS * N_QKV;
  u16* hsH  = qkvL + (size_t)M_ROWS * QKL_N;
  u16* hsL  = hsH + (size_t)M_ROWS * D_EMB;
  u16* vt   = hsL + (size_t)M_ROWS * D_EMB;
  u16* wtH  = vt;                                   // alias (disjoint lifetime)
  u16* wtL  = wtH + (size_t)N_QKV * D_EMB;
  u16* attnH = hsH;                                 // alias (hs dead after GEMM1)
  u16* attnL = hsL;

  // 1) split hidden_states
  {
    int n4 = (M_ROWS * D_EMB) / 4;
    split_kernel<<<(n4 + 255) / 256, 256, 0, stream>>>(hs, hsH, hsL, n4);
  }
  // 2) transpose+split w_qkv -> wt (in vt region)
  {
    dim3 g(N_QKV / 32, D_EMB / 32);
    transpose_split_kernel<<<g, 256, 0, stream>>>(wqkv, wtH, wtL, D_EMB, N_QKV);
  }
  // 3) QKV GEMM (deep pipeline + XCD swizzle): 33 cols x 40 bands
  {
    gemm8p_kernel<1><<<33 * 40, 512, 0, stream>>>(hsH, hsL, wtH, wtL, bqkv,
                                                  nullptr, qkvH, qkvL,
                                                  M_ROWS, N_QKV, 33);
  }
  // 4) V transpose (wt dead; vt region reused)
  {
    dim3 g(SP / 64, BATCH * NHEADS);
    vtrans_kernel<<<g, 256, 0, stream>>>(qkvH, vt);
  }
  // 5) attention
  {
    dim3 g(SP / QT, NHEADS, BATCH);
    attn_kernel2<<<g, 256, 0, stream>>>(qkvH, qkvL, vt, attnH, attnL);
  }
  // 6) transpose+split w_proj -> wt (vt dead)
  {
    dim3 g(D_EMB / 32, D_EMB / 32);
    transpose_split_kernel<<<g, 256, 0, stream>>>(wproj, wtH, wtL, D_EMB, D_EMB);
  }
  // 7) output projection: 11 cols x 40 bands
  {
    gemm8p_kernel<0><<<11 * 40, 512, 0, stream>>>(attnH, attnL, wtH, wtL, bproj,
                                                  out, nullptr, nullptr,
                                                  M_ROWS, D_EMB, 11);
  }
}

// Round 5
// 866.974 us; speedup vs baseline: 1.0955x; 1.0250x over previous
//
#include <hip/hip_runtime.h>
#include <cstddef>
#include <cstdint>

#define D_EMB   1408
#define NHEADS  16
#define HD      88
#define BATCH   16
#define SEQ     577
#define M_ROWS  (BATCH * SEQ)   // 9232
#define N_QKV   (3 * D_EMB)     // 4224
#define QKL_N   2816            // qkv-lo row stride (Q|K thirds only)
#define SP      640             // seq padded to 10 x 64 for Vt
#define ATT_SCALE 0.10660035817780521f

#define QT 64
#define KT 64

typedef __attribute__((ext_vector_type(8))) short bf16x8;
typedef __attribute__((ext_vector_type(4))) float f32x4;
typedef unsigned short u16;

static __device__ __forceinline__ u16 f2bf(float x) {
  union { float f; unsigned u; } v; v.f = x;
  unsigned r = v.u + 0x7fff + ((v.u >> 16) & 1);   // RNE
  return (u16)(r >> 16);
}
static __device__ __forceinline__ float bf2f(u16 h) {
  union { unsigned u; float f; } v; v.u = ((unsigned)h) << 16;
  return v.f;
}
static __device__ __forceinline__ void split_hl(float x, u16* hi, u16* lo) {
  u16 h = f2bf(x);
  *hi = h;
  *lo = f2bf(x - bf2f(h));
}

// async global->LDS, 16 B per lane; lds dest = wave-uniform base + lane*16
static __device__ __forceinline__ void async16(const u16* g, u16* l) {
  __builtin_amdgcn_global_load_lds(
      (const __attribute__((address_space(1))) unsigned int*)g,
      (__attribute__((address_space(3))) unsigned int*)l, 16, 0, 0);
}

// ---------------------------------------------------------------------------
// split: X fp32 -> H,L bf16
// ---------------------------------------------------------------------------
__global__ __launch_bounds__(256)
void split_kernel(const float* __restrict__ X, u16* __restrict__ H,
                  u16* __restrict__ L, int n4) {
  int i = blockIdx.x * 256 + threadIdx.x;
  if (i >= n4) return;
  float4 v = ((const float4*)X)[i];
  ushort4 h, l;
  split_hl(v.x, &h.x, &l.x);
  split_hl(v.y, &h.y, &l.y);
  split_hl(v.z, &h.z, &l.z);
  split_hl(v.w, &h.w, &l.w);
  ((ushort4*)H)[i] = h;
  ((ushort4*)L)[i] = l;
}

// ---------------------------------------------------------------------------
// transpose+split: W[K][N] fp32 -> Th,Tl[N][K] bf16
// ---------------------------------------------------------------------------
__global__ __launch_bounds__(256)
void transpose_split_kernel(const float* __restrict__ W, u16* __restrict__ Th,
                            u16* __restrict__ Tl, int K, int N) {
  __shared__ float tile[32][33];
  const int n0 = blockIdx.x * 32, k0 = blockIdx.y * 32;
  const int tx = threadIdx.x & 31, ty = threadIdx.x >> 5;
#pragma unroll
  for (int i = 0; i < 4; ++i) {
    int k = ty + i * 8;
    tile[k][tx] = W[(size_t)(k0 + k) * N + n0 + tx];
  }
  __syncthreads();
#pragma unroll
  for (int i = 0; i < 4; ++i) {
    int n = ty + i * 8;
    float v = tile[tx][n];
    u16 h, l;
    split_hl(v, &h, &l);
    Th[(size_t)(n0 + n) * K + k0 + tx] = h;
    Tl[(size_t)(n0 + n) * K + k0 + tx] = l;
  }
}

// ---------------------------------------------------------------------------
// V transpose: qkvH V-third -> vt[bh][d][s], [256][96][640], zero-padded.
// ---------------------------------------------------------------------------
__global__ __launch_bounds__(256)
void vtrans_kernel(const u16* __restrict__ qkvh, u16* __restrict__ vt) {
  __shared__ u16 tile[64][96];   // [s][d]
  const int st = blockIdx.x, bh = blockIdx.y;
  const int b = bh >> 4, h = bh & 15;
  const int tid = threadIdx.x;
  const int s0 = st * 64;
  for (int idx = tid; idx < 64 * 22; idx += 256) {
    int j = idx / 22, c4 = (idx % 22) * 4;
    int s = s0 + j;
    ushort4 v = make_ushort4(0, 0, 0, 0);
    if (s < SEQ)
      v = *(const ushort4*)(qkvh + (size_t)(b * SEQ + s) * N_QKV + 2 * D_EMB + h * HD + c4);
    *(ushort4*)&tile[j][c4] = v;
  }
  if (tid < 64) {
    bf16x8 z = {0, 0, 0, 0, 0, 0, 0, 0};
    *(bf16x8*)&tile[tid][88] = z;
  }
  __syncthreads();
  for (int idx = tid; idx < 96 * 8; idx += 256) {
    int d = idx >> 3, c8 = (idx & 7) * 8;
    bf16x8 o;
#pragma unroll
    for (int e = 0; e < 8; ++e) o[e] = (short)tile[c8 + e][d];
    *(bf16x8*)(vt + ((size_t)bh * 96 + d) * SP + s0 + c8) = o;
  }
}

// ---------------------------------------------------------------------------
// 3-product hi/lo bf16 MFMA GEMM, m201 geometry: BM=256 x BN=256, BK=32,
// 8 waves 2M x 4N, per-wave 128x64 (acc 8x4 frags). LDS-read:MFMA cycle
// ratio 0.61 (was 1.03 at 64x64/wave) -- the R3 post-mortem limiter.
// Ring-2 LDS (2 x 64 KiB), stage-ahead-1; stage issued in ph0/ph1, waited
// at slot end (~2 phases ~ 2000 cyc distance, covers HBM latency).
// Slot = 4 phases (i-pairs of the per-wave tile); B-frags read once in ph0
// and held in registers for the whole slot.
// Swizzle: 16B block q of row r at phys q ^ ((r>>1)&3) (conflict-free).
// XCD-swizzled 1-D grid. MODE 0: fp32 out. MODE 1: hi/lo split out.
// ---------------------------------------------------------------------------
#define KDIM   1408
#define BMT    256
#define BNT    256
#define SLOT_E 32768          // elems per slot: A 2*8192 + B 2*8192 = 64 KiB
#define AS_H   0
#define AS_L   8192
#define BS_H   16384
#define BS_L   24576

#define STG_A(SLOTP, SSN)                                                 \
  {                                                                       \
    const int k0s = (SSN) * 32;                                           \
    u16* Ls = &Lds[SLOTP][0];                                             \
    async16(Ah + srcA0 + k0s, Ls + AS_H + ldsD0);                         \
    async16(Al + srcA0 + k0s, Ls + AS_L + ldsD0);                         \
    async16(Ah + srcA1 + k0s, Ls + AS_H + ldsD1);                         \
    async16(Al + srcA1 + k0s, Ls + AS_L + ldsD1);                         \
  }
#define STG_B(SLOTP, SSN)                                                 \
  {                                                                       \
    const int k0s = (SSN) * 32;                                           \
    u16* Ls = &Lds[SLOTP][0];                                             \
    async16(Bh + srcB0 + k0s, Ls + BS_H + ldsD0);                         \
    async16(Bl + srcB0 + k0s, Ls + BS_L + ldsD0);                         \
    async16(Bh + srcB1 + k0s, Ls + BS_H + ldsD1);                         \
    async16(Bl + srcB1 + k0s, Ls + BS_L + ldsD1);                         \
  }

#define MFMA3(ACC, AH, AL, BH, BL)                                                  \
  ACC = __builtin_amdgcn_mfma_f32_16x16x32_bf16(AH, BH, ACC, 0, 0, 0);              \
  ACC = __builtin_amdgcn_mfma_f32_16x16x32_bf16(AH, BL, ACC, 0, 0, 0);              \
  ACC = __builtin_amdgcn_mfma_f32_16x16x32_bf16(AL, BH, ACC, 0, 0, 0);

#define ROW_MFMA(I, AH, AL)                                               \
  MFMA3(acc[I][0], AH, AL, fbh0, fbl0)                                    \
  MFMA3(acc[I][1], AH, AL, fbh1, fbl1)                                    \
  MFMA3(acc[I][2], AH, AL, fbh2, fbl2)                                    \
  MFMA3(acc[I][3], AH, AL, fbh3, fbl3)

#define PH_SYNC                                                           \
  __builtin_amdgcn_s_barrier();                                           \
  asm volatile("s_waitcnt lgkmcnt(0)" ::: "memory");                      \
  __builtin_amdgcn_sched_barrier(0);

// One K-32 slot: compute from phys PHYS, stage slot SSN into phys PHYS^1.
#define SLOT_RUN(PHYS, SSN, DO_STAGE, DO_VM)                              \
  {                                                                       \
    const u16* Lb = &Lds[PHYS][0];                                        \
    bf16x8 fbh0, fbh1, fbh2, fbh3, fbl0, fbl1, fbl2, fbl3;                \
    bf16x8 a0h, a0l, a1h, a1l;                                            \
    /* ---- ph0: read all B + A rows 0,1 ---- */                          \
    fbh0 = *(const bf16x8*)&Lb[BS_H + offB[0]];                           \
    fbh1 = *(const bf16x8*)&Lb[BS_H + offB[1]];                           \
    fbh2 = *(const bf16x8*)&Lb[BS_H + offB[2]];                           \
    fbh3 = *(const bf16x8*)&Lb[BS_H + offB[3]];                           \
    fbl0 = *(const bf16x8*)&Lb[BS_L + offB[0]];                           \
    fbl1 = *(const bf16x8*)&Lb[BS_L + offB[1]];                           \
    fbl2 = *(const bf16x8*)&Lb[BS_L + offB[2]];                           \
    fbl3 = *(const bf16x8*)&Lb[BS_L + offB[3]];                           \
    a0h = *(const bf16x8*)&Lb[AS_H + offA[0]];                            \
    a0l = *(const bf16x8*)&Lb[AS_L + offA[0]];                            \
    a1h = *(const bf16x8*)&Lb[AS_H + offA[1]];                            \
    a1l = *(const bf16x8*)&Lb[AS_L + offA[1]];                            \
    if (DO_STAGE) STG_A(PHYS ^ 1, SSN);                                   \
    PH_SYNC                                                               \
    __builtin_amdgcn_s_setprio(1);                                        \
    ROW_MFMA(0, a0h, a0l) ROW_MFMA(1, a1h, a1l)                           \
    __builtin_amdgcn_s_setprio(0);                                        \
    __builtin_amdgcn_s_barrier();                                         \
    /* ---- ph1: A rows 2,3 ---- */                                       \
    a0h = *(const bf16x8*)&Lb[AS_H + offA[2]];                            \
    a0l = *(const bf16x8*)&Lb[AS_L + offA[2]];                            \
    a1h = *(const bf16x8*)&Lb[AS_H + offA[3]];                            \
    a1l = *(const bf16x8*)&Lb[AS_L + offA[3]];                            \
    if (DO_STAGE) STG_B(PHYS ^ 1, SSN);                                   \
    PH_SYNC                                                               \
    __builtin_amdgcn_s_setprio(1);                                        \
    ROW_MFMA(2, a0h, a0l) ROW_MFMA(3, a1h, a1l)                           \
    __builtin_amdgcn_s_setprio(0);                                        \
    __builtin_amdgcn_s_barrier();                                         \
    /* ---- ph2: A rows 4,5 ---- */                                       \
    a0h = *(const bf16x8*)&Lb[AS_H + offA[4]];                            \
    a0l = *(const bf16x8*)&Lb[AS_L + offA[4]];                            \
    a1h = *(const bf16x8*)&Lb[AS_H + offA[5]];                            \
    a1l = *(const bf16x8*)&Lb[AS_L + offA[5]];                            \
    PH_SYNC                                                               \
    __builtin_amdgcn_s_setprio(1);                                        \
    ROW_MFMA(4, a0h, a0l) ROW_MFMA(5, a1h, a1l)                           \
    __builtin_amdgcn_s_setprio(0);                                        \
    __builtin_amdgcn_s_barrier();                                         \
    /* ---- ph3: A rows 6,7 ---- */                                       \
    a0h = *(const bf16x8*)&Lb[AS_H + offA[6]];                            \
    a0l = *(const bf16x8*)&Lb[AS_L + offA[6]];                            \
    a1h = *(const bf16x8*)&Lb[AS_H + offA[7]];                            \
    a1l = *(const bf16x8*)&Lb[AS_L + offA[7]];                            \
    PH_SYNC                                                               \
    __builtin_amdgcn_s_setprio(1);                                        \
    ROW_MFMA(6, a0h, a0l) ROW_MFMA(7, a1h, a1l)                           \
    __builtin_amdgcn_s_setprio(0);                                        \
    if (DO_VM) asm volatile("s_waitcnt vmcnt(0)" ::: "memory");           \
    __builtin_amdgcn_s_barrier();                                         \
  }

template <int MODE>
__global__ __launch_bounds__(512)
void gemm8p_kernel(const u16* __restrict__ Ah, const u16* __restrict__ Al,
                   const u16* __restrict__ Bh, const u16* __restrict__ Bl,
                   const float* __restrict__ bias,
                   float* __restrict__ Cf, u16* __restrict__ Ch, u16* __restrict__ Cl,
                   int M, int N, int NX) {
  const int lin  = blockIdx.x;
  const int xcd  = lin & 7;
  const int t    = lin >> 3;
  const int band = xcd + 8 * (t / NX);
  const int bm0  = band * BMT;
  if (bm0 >= M) return;
  const int bn0  = (t % NX) * BNT;

  __shared__ u16 Lds[2][SLOT_E];   // 128 KiB ring-2

  const int tid  = threadIdx.x;
  const int lane = tid & 63;
  const int w    = tid >> 6;           // 8 waves
  const int quad = lane >> 4, lc = lane & 15;
  const int wm   = w >> 2, wn = w & 3; // 2M x 4N, per-wave 128x64

  // ---- staging source/dest (per thread; add SSN*32 per slot) ----
  size_t srcA0, srcA1, srcB0, srcB1;
  int ldsD0, ldsD1;
  {
    int r0 = tid >> 2, q0 = tid & 3;            // rows 0..127, 4 chunks of K=32
    int swz0 = (q0 ^ ((r0 >> 1) & 3)) * 8;
    int r1 = 128 + r0;
    int swz1 = (q0 ^ ((r1 >> 1) & 3)) * 8;
    int ra0 = bm0 + r0; if (ra0 > M - 1) ra0 = M - 1;
    int ra1 = bm0 + r1; if (ra1 > M - 1) ra1 = M - 1;
    srcA0 = (size_t)ra0 * KDIM + swz0;
    srcA1 = (size_t)ra1 * KDIM + swz1;
    int rb0 = bn0 + r0; if (rb0 > N - 1) rb0 = N - 1;
    int rb1 = bn0 + r1; if (rb1 > N - 1) rb1 = N - 1;
    srcB0 = (size_t)rb0 * KDIM + swz0;
    srcB1 = (size_t)rb1 * KDIM + swz1;
    ldsD0 = w * 512;           // rows 0..127 region (4096 elems)
    ldsD1 = 4096 + w * 512;    // rows 128..255 region
  }

  // ---- fragment read offsets (elems within array region) ----
  int offA[8], offB[4];
  {
    const int qphys = quad ^ ((lc >> 1) & 3);
#pragma unroll
    for (int i = 0; i < 8; ++i)
      offA[i] = (wm * 128 + i * 16 + lc) * 32 + qphys * 8;
#pragma unroll
    for (int j = 0; j < 4; ++j)
      offB[j] = (wn * 64 + j * 16 + lc) * 32 + qphys * 8;
  }

  f32x4 acc[8][4];
#pragma unroll
  for (int i = 0; i < 8; ++i)
#pragma unroll
    for (int j = 0; j < 4; ++j) acc[i][j] = (f32x4){0.f, 0.f, 0.f, 0.f};

  // ---- prologue: stage slot 0 into phys 0; wait; enter loop ----
  STG_A(0, 0);
  STG_B(0, 0);
  asm volatile("s_waitcnt vmcnt(0)" ::: "memory");
  __builtin_amdgcn_s_barrier();

  // ---- main loop: 44 slots (K=1408), ring-2 stage-ahead-1 ----
#pragma unroll 1
  for (int u = 0; u < 21; ++u) {
    SLOT_RUN(0, 2 * u + 1, true, true);
    SLOT_RUN(1, 2 * u + 2, true, true);
  }
  SLOT_RUN(0, 43, true, true);     // slot 42, stages slot 43
  SLOT_RUN(1, 0, false, false);    // slot 43

  // ---- epilogue: C/D layout col=lc, row=quad*4+reg ----
#pragma unroll
  for (int j = 0; j < 4; ++j) {
    int col = bn0 + wn * 64 + j * 16 + lc;
    if (col < N) {
      float bj = bias[col];
#pragma unroll
      for (int i = 0; i < 8; ++i) {
#pragma unroll
        for (int rg = 0; rg < 4; ++rg) {
          int row = bm0 + wm * 128 + i * 16 + quad * 4 + rg;
          if (row < M) {
            float v = acc[i][j][rg] + bj;
            if (MODE == 0) {
              Cf[(size_t)row * N + col] = v;
            } else {
              u16 hh, ll;
              split_hl(v, &hh, &ll);
              Ch[(size_t)row * N + col] = hh;
              if (col < QKL_N) Cl[(size_t)row * QKL_N + col] = ll;
            }
          }
        }
      }
    }
  }
}

// ---------------------------------------------------------------------------
// MFMA flash attention v2 (round-4, kept). Block = (b,h,64-q tile).
// ---------------------------------------------------------------------------
__global__ __launch_bounds__(256)
void attn_kernel2(const u16* __restrict__ qkvh, const u16* __restrict__ qkvl,
                  const u16* __restrict__ vt,
                  u16* __restrict__ outh, u16* __restrict__ outl) {
  __shared__ u16 Khi[KT][104];   // stride 52 words == 20 mod 32 -> <=2-way
  __shared__ u16 Klo[KT][104];
  __shared__ u16 Vs[96][72];     // stride 36 words == 4 mod 32 -> <=2-way
  __shared__ u16 Pb[QT][72];

  const int tid  = threadIdx.x;
  const int lane = tid & 63;
  const int wv   = tid >> 6;
  const int quad = lane >> 4;
  const int lc   = lane & 15;

  const int qt = blockIdx.x, h = blockIdx.y, b = blockIdx.z;
  const int q0 = qt * QT;

  if (tid < KT) {
    bf16x8 z = {0, 0, 0, 0, 0, 0, 0, 0};
    *(bf16x8*)&Khi[tid][88] = z;
    *(bf16x8*)&Klo[tid][88] = z;
  }

  bf16x8 qh[3], ql[3];
  {
    const bf16x8 z = {0, 0, 0, 0, 0, 0, 0, 0};
    int qrow = q0 + wv * 16 + lc;
    bool qv = qrow < SEQ;
    size_t bh_ = (size_t)(b * SEQ + (qv ? qrow : 0));
#pragma unroll
    for (int ks = 0; ks < 3; ++ks) {
      if (!qv || (ks == 2 && quad == 3)) {
        qh[ks] = z; ql[ks] = z;
      } else {
        qh[ks] = *(const bf16x8*)(qkvh + bh_ * N_QKV + h * HD + ks * 32 + quad * 8);
        ql[ks] = *(const bf16x8*)(qkvl + bh_ * QKL_N + h * HD + ks * 32 + quad * 8);
      }
    }
  }

  float mrow[4], lrow[4];
#pragma unroll
  for (int r = 0; r < 4; ++r) { mrow[r] = -INFINITY; lrow[r] = 0.f; }
  f32x4 oacc[6];
#pragma unroll
  for (int nn = 0; nn < 6; ++nn) oacc[nn] = (f32x4){0.f, 0.f, 0.f, 0.f};

  const u16* vsrc = vt + (size_t)(b * 16 + h) * 96 * SP;

  for (int kt = 0; kt < SP / KT; ++kt) {
    const int k0 = kt * KT;
    __syncthreads();

    for (int idx = tid; idx < KT * 22; idx += 256) {
      int j = idx / 22, c4 = (idx % 22) * 4;
      int s = k0 + j;
      ushort4 kh = make_ushort4(0, 0, 0, 0), kl = make_ushort4(0, 0, 0, 0);
      if (s < SEQ) {
        size_t rb = (size_t)(b * SEQ + s);
        kh = *(const ushort4*)(qkvh + rb * N_QKV + D_EMB + h * HD + c4);
        kl = *(const ushort4*)(qkvl + rb * QKL_N + D_EMB + h * HD + c4);
      }
      *(ushort4*)&Khi[j][c4] = kh;
      *(ushort4*)&Klo[j][c4] = kl;
    }
    for (int idx = tid; idx < 96 * 8; idx += 256) {
      int d = idx >> 3, c8 = (idx & 7) * 8;
      *(bf16x8*)&Vs[d][c8] = *(const bf16x8*)(vsrc + (size_t)d * SP + k0 + c8);
    }
    __syncthreads();

    f32x4 sc[4];
#pragma unroll
    for (int t = 0; t < 4; ++t) {
      f32x4 a = (f32x4){0.f, 0.f, 0.f, 0.f};
#pragma unroll
      for (int ks = 0; ks < 3; ++ks) {
        bf16x8 kh = *(const bf16x8*)&Khi[t * 16 + lc][ks * 32 + quad * 8];
        bf16x8 kl = *(const bf16x8*)&Klo[t * 16 + lc][ks * 32 + quad * 8];
        a = __builtin_amdgcn_mfma_f32_16x16x32_bf16(qh[ks], kh, a, 0, 0, 0);
        a = __builtin_amdgcn_mfma_f32_16x16x32_bf16(qh[ks], kl, a, 0, 0, 0);
        a = __builtin_amdgcn_mfma_f32_16x16x32_bf16(ql[ks], kh, a, 0, 0, 0);
      }
      sc[t] = a;
    }
#pragma unroll
    for (int t = 0; t < 4; ++t) {
      bool valid = (k0 + t * 16 + lc) < SEQ;
#pragma unroll
      for (int r = 0; r < 4; ++r)
        sc[t][r] = valid ? sc[t][r] * ATT_SCALE : -INFINITY;
    }

    float alpha[4];
#pragma unroll
    for (int r = 0; r < 4; ++r) {
      float v = fmaxf(fmaxf(sc[0][r], sc[1][r]), fmaxf(sc[2][r], sc[3][r]));
      v = fmaxf(v, __shfl_xor(v, 1));
      v = fmaxf(v, __shfl_xor(v, 2));
      v = fmaxf(v, __shfl_xor(v, 4));
      v = fmaxf(v, __shfl_xor(v, 8));
      float mnew = fmaxf(mrow[r], v);
      alpha[r] = expf(mrow[r] - mnew);
      mrow[r] = mnew;
      float s = 0.f;
#pragma unroll
      for (int t = 0; t < 4; ++t) {
        float p = expf(sc[t][r] - mnew);
        sc[t][r] = p;
        s += p;
      }
      s += __shfl_xor(s, 1);
      s += __shfl_xor(s, 2);
      s += __shfl_xor(s, 4);
      s += __shfl_xor(s, 8);
      lrow[r] = lrow[r] * alpha[r] + s;
    }
#pragma unroll
    for (int t = 0; t < 4; ++t)
#pragma unroll
      for (int r = 0; r < 4; ++r)
        Pb[wv * 16 + quad * 4 + r][t * 16 + lc] = f2bf(sc[t][r]);
#pragma unroll
    for (int nn = 0; nn < 6; ++nn)
#pragma unroll
      for (int r = 0; r < 4; ++r) oacc[nn][r] *= alpha[r];
    __syncthreads();

    bf16x8 p0 = *(const bf16x8*)&Pb[wv * 16 + lc][quad * 8];
    bf16x8 p1 = *(const bf16x8*)&Pb[wv * 16 + lc][32 + quad * 8];
#pragma unroll
    for (int nn = 0; nn < 6; ++nn) {
      bf16x8 v0 = *(const bf16x8*)&Vs[nn * 16 + lc][quad * 8];
      bf16x8 v1 = *(const bf16x8*)&Vs[nn * 16 + lc][32 + quad * 8];
      oacc[nn] = __builtin_amdgcn_mfma_f32_16x16x32_bf16(p0, v0, oacc[nn], 0, 0, 0);
      oacc[nn] = __builtin_amdgcn_mfma_f32_16x16x32_bf16(p1, v1, oacc[nn], 0, 0, 0);
    }
  }

#pragma unroll
  for (int r = 0; r < 4; ++r) {
    int s = q0 + wv * 16 + quad * 4 + r;
    if (s < SEQ) {
      float inv = 1.f / lrow[r];
      size_t base = (size_t)(b * SEQ + s) * D_EMB + h * HD;
#pragma unroll
      for (int nn = 0; nn < 6; ++nn) {
        int d = nn * 16 + lc;
        if (d < HD) {
          float v = oacc[nn][r] * inv;
          u16 hh, ll;
          split_hl(v, &hh, &ll);
          outh[base + d] = hh;
          outl[base + d] = ll;
        }
      }
    }
  }
}

// ---------------------------------------------------------------------------
extern "C" void kernel_launch(void* const* d_in, const int* in_sizes, int n_in,
                              void* d_out, int out_size, void* d_ws, size_t ws_size,
                              hipStream_t stream) {
  const float* hs    = (const float*)d_in[0];
  const float* wqkv  = (const float*)d_in[1];
  const float* bqkv  = (const float*)d_in[2];
  const float* wproj = (const float*)d_in[3];
  const float* bproj = (const float*)d_in[4];
  float* out = (float*)d_out;

  u16* qkvH = (u16*)d_ws;
  u16* qkvL = qkvH + (size_t)M_ROWS * N_QKV;
  u16* hsH  = qkvL + (size_t)M_ROWS * QKL_N;
  u16* hsL  = hsH + (size_t)M_ROWS * D_EMB;
  u16* vt   = hsL + (size_t)M_ROWS * D_EMB;
  u16* wtH  = vt;                                   // alias (disjoint lifetime)
  u16* wtL  = wtH + (size_t)N_QKV * D_EMB;
  u16* attnH = hsH;                                 // alias (hs dead after GEMM1)
  u16* attnL = hsL;

  // 1) split hidden_states
  {
    int n4 = (M_ROWS * D_EMB) / 4;
    split_kernel<<<(n4 + 255) / 256, 256, 0, stream>>>(hs, hsH, hsL, n4);
  }
  // 2) transpose+split w_qkv -> wt (in vt region)
  {
    dim3 g(N_QKV / 32, D_EMB / 32);
    transpose_split_kernel<<<g, 256, 0, stream>>>(wqkv, wtH, wtL, D_EMB, N_QKV);
  }
  // 3) QKV GEMM: 17 col-blocks (last partial) x 40 padded bands
  {
    gemm8p_kernel<1><<<17 * 40, 512, 0, stream>>>(hsH, hsL, wtH, wtL, bqkv,
                                                  nullptr, qkvH, qkvL,
                                                  M_ROWS, N_QKV, 17);
  }
  // 4) V transpose (wt dead; vt region reused)
  {
    dim3 g(SP / 64, BATCH * NHEADS);
    vtrans_kernel<<<g, 256, 0, stream>>>(qkvH, vt);
  }
  // 5) attention
  {
    dim3 g(SP / QT, NHEADS, BATCH);
    attn_kernel2<<<g, 256, 0, stream>>>(qkvH, qkvL, vt, attnH, attnL);
  }
  // 6) transpose+split w_proj -> wt (vt dead)
  {
    dim3 g(D_EMB / 32, D_EMB / 32);
    transpose_split_kernel<<<g, 256, 0, stream>>>(wproj, wtH, wtL, D_EMB, D_EMB);
  }
  // 7) output projection: 6 col-blocks (last partial) x 40 padded bands
  {
    gemm8p_kernel<0><<<6 * 40, 512, 0, stream>>>(attnH, attnL, wtH, wtL, bproj,
                                                 out, nullptr, nullptr,
                                                 M_ROWS, D_EMB, 6);
  }
}